// Round 1
// 855.567 us; speedup vs baseline: 1.0658x; 1.0658x over previous
//
#include <hip/hip_runtime.h>
#include <hip/hip_bf16.h>
#include <math.h>

// MambaActorCritic: B=2048, OBS=512, D_MODEL=1024, D_INNER=2048, D_STATE=16,
// D_CONV=4, DT_RANK=64, ACT=18. All inputs/outputs fp32; big GEMMs in bf16 MFMA.
//
// v2 changes vs 912us baseline:
//  - G5 (out = y @ out_proj^T) REMOVED: out is not a model output; heads fold
//    out_proj into Wc = [pol_w;val_w] @ out_proj_w (fp32) and read y_bf directly.
//  - conv fused into G2 epilogue (xz buffer + conv_kernel removed).
//  - dt_kernel batches 8 b-rows/block (dt_w reuse in regs, L2 traffic /8).
//  - ssm_kernel: 4 lanes per channel -> fully coalesced state read/write.

#define BATCH 2048
#define OBSD 512
#define DMODEL 1024
#define DINNER 2048
#define DSTATE 16
#define DTRANK 64
#define NACT 18

typedef __attribute__((ext_vector_type(8))) short shortx8;
typedef __attribute__((ext_vector_type(4))) float floatx4;

__device__ inline float sig_(float x) { return 1.f / (1.f + __expf(-x)); }

__device__ inline unsigned short bfc(float x) {
    __hip_bfloat16 h = __float2bfloat16(x);
    return *(unsigned short*)&h;
}

__device__ inline void store_bf4(unsigned short* dst, float4 v) {
    ushort4 u;
    u.x = bfc(v.x); u.y = bfc(v.y); u.z = bfc(v.z); u.w = bfc(v.w);
    *(ushort4*)dst = u;
}

// ---------------------------------------------------------------------------
// Convert fp32 -> bf16 for MFMA operands, plus A = -exp(A_log).
// Segments (float4 groups): obs 262144 | in_proj_w 131072 | mamba_in_w 1048576
// | x_proj_w padded 96->128 rows: 65536 | A_log 8192  => 1,515,520 groups
// grid 5920 x 256 (exact).
// ---------------------------------------------------------------------------
__global__ __launch_bounds__(256) void convert_kernel(
    const float* __restrict__ obs, const float* __restrict__ w1,
    const float* __restrict__ w2, const float* __restrict__ w3,
    const float* __restrict__ Alog,
    unsigned short* __restrict__ obs_bf, unsigned short* __restrict__ w1_bf,
    unsigned short* __restrict__ w2_bf, unsigned short* __restrict__ w3_bf,
    float* __restrict__ A_neg)
{
    int g = blockIdx.x * 256 + threadIdx.x;
    if (g < 262144) {
        store_bf4(obs_bf + g * 4, ((const float4*)obs)[g]);
    } else if (g < 393216) {
        int t = g - 262144;
        store_bf4(w1_bf + t * 4, ((const float4*)w1)[t]);
    } else if (g < 1441792) {
        int t = g - 393216;
        store_bf4(w2_bf + t * 4, ((const float4*)w2)[t]);
    } else if (g < 1507328) {
        int t = g - 1441792;
        int e = t * 4;
        int n = e >> 11;
        int k = e & 2047;
        float4 v = {0.f, 0.f, 0.f, 0.f};
        if (n < 96) v = *(const float4*)(w3 + n * 2048 + k);
        store_bf4(w3_bf + e, v);
    } else {
        int t = g - 1507328;  // < 8192
        float4 v = ((const float4*)Alog)[t];
        float4 o = {-__expf(v.x), -__expf(v.y), -__expf(v.z), -__expf(v.w)};
        ((float4*)A_neg)[t] = o;
    }
}

// ---------------------------------------------------------------------------
// m97-style bf16 MFMA GEMM: C[M,N] = A[M,K] * B[N,K]^T (both K-contiguous).
// 128x128 block tile, 4 waves each computing 64x64 (4x4 of 16x16x32 MFMA),
// BK=32, global_load_lds width 16 staging, 2-barrier K-loop.
// ---------------------------------------------------------------------------
template <int BF16OUT, int BIAS, int SPLITK>
__global__ __launch_bounds__(256) void gemm_bt(
    const short* __restrict__ A, const short* __restrict__ Bm,
    void* __restrict__ Cout, const float* __restrict__ bias,
    int M, int N, int K, int ksplit_len)
{
    __shared__ short As[128 * 32];
    __shared__ short Bs[128 * 32];

    const int tid  = threadIdx.x;
    const int wave = tid >> 6;
    const int lane = tid & 63;
    const int quad = lane >> 4;
    const int l16  = lane & 15;
    const int wm   = (wave & 1) << 6;
    const int wn   = (wave >> 1) << 6;
    const int bm   = blockIdx.x;
    const int bn   = blockIdx.y;

    int kbeg = 0, kend = K;
    if (SPLITK) { kbeg = blockIdx.z * ksplit_len; kend = kbeg + ksplit_len; }

    floatx4 acc[4][4] = {};

    const int v0 = tid * 8;
    const int r0 = v0 >> 5, c0 = v0 & 31;
    const int v1 = (256 + tid) * 8;
    const int r1 = v1 >> 5, c1 = v1 & 31;

    const short* Abase = A + (size_t)bm * 128 * K;
    const short* Bbase = Bm + (size_t)bn * 128 * K;

    for (int k0 = kbeg; k0 < kend; k0 += 32) {
        __syncthreads();
        __builtin_amdgcn_global_load_lds(
            (const __attribute__((address_space(1))) unsigned int*)(Abase + (size_t)r0 * K + k0 + c0),
            (__attribute__((address_space(3))) unsigned int*)(As + wave * 512), 16, 0, 0);
        __builtin_amdgcn_global_load_lds(
            (const __attribute__((address_space(1))) unsigned int*)(Abase + (size_t)r1 * K + k0 + c1),
            (__attribute__((address_space(3))) unsigned int*)(As + 2048 + wave * 512), 16, 0, 0);
        __builtin_amdgcn_global_load_lds(
            (const __attribute__((address_space(1))) unsigned int*)(Bbase + (size_t)r0 * K + k0 + c0),
            (__attribute__((address_space(3))) unsigned int*)(Bs + wave * 512), 16, 0, 0);
        __builtin_amdgcn_global_load_lds(
            (const __attribute__((address_space(1))) unsigned int*)(Bbase + (size_t)r1 * K + k0 + c1),
            (__attribute__((address_space(3))) unsigned int*)(Bs + 2048 + wave * 512), 16, 0, 0);
        __syncthreads();

        shortx8 af[4], bfv[4];
#pragma unroll
        for (int i = 0; i < 4; ++i)
            af[i] = *(const shortx8*)(As + (wm + i * 16 + l16) * 32 + quad * 8);
#pragma unroll
        for (int j = 0; j < 4; ++j)
            bfv[j] = *(const shortx8*)(Bs + (wn + j * 16 + l16) * 32 + quad * 8);
#pragma unroll
        for (int i = 0; i < 4; ++i)
#pragma unroll
            for (int j = 0; j < 4; ++j)
                acc[i][j] = __builtin_amdgcn_mfma_f32_16x16x32_bf16(af[i], bfv[j], acc[i][j], 0, 0, 0);
    }

    // epilogue: C/D layout col(n)=lane&15, row(m)=quad*4+reg  [m89-verified]
    if (BF16OUT) {
        unsigned short* C = (unsigned short*)Cout;
#pragma unroll
        for (int i = 0; i < 4; ++i) {
            int gm = bm * 128 + wm + i * 16 + quad * 4;
#pragma unroll
            for (int j = 0; j < 4; ++j) {
                int gn = bn * 128 + wn + j * 16 + l16;
                float bv = BIAS ? bias[gn] : 0.f;
#pragma unroll
                for (int r = 0; r < 4; ++r)
                    C[(size_t)(gm + r) * N + gn] = bfc(acc[i][j][r] + bv);
            }
        }
    } else {
        float* C = (float*)Cout;
        if (SPLITK) C += (size_t)blockIdx.z * M * N;
#pragma unroll
        for (int i = 0; i < 4; ++i) {
            int gm = bm * 128 + wm + i * 16 + quad * 4;
#pragma unroll
            for (int j = 0; j < 4; ++j) {
                int gn = bn * 128 + wn + j * 16 + l16;
                float bv = BIAS ? bias[gn] : 0.f;
#pragma unroll
                for (int r = 0; r < 4; ++r)
                    C[(size_t)(gm + r) * N + gn] = acc[i][j][r] + bv;
            }
        }
    }
}

// ---------------------------------------------------------------------------
// G2 with fused conv/z epilogue: xz = h @ mamba_in_w.T (M=2048, N=4096, K=1024)
// x half (n<2048): conv_state shift + conv + silu -> conv_out, x_conv, x_conv_bf
// z half (n>=2048): zs = z * sigmoid(z)
// No xz buffer ever touches memory.
// ---------------------------------------------------------------------------
__global__ __launch_bounds__(256) void gemm_g2(
    const short* __restrict__ A, const short* __restrict__ Bm,
    const float* __restrict__ conv_state, const float* __restrict__ conv_w,
    const float* __restrict__ conv_b, float* __restrict__ conv_out,
    float* __restrict__ x_conv, unsigned short* __restrict__ x_conv_bf,
    float* __restrict__ zs, int K)
{
    __shared__ short As[128 * 32];
    __shared__ short Bs[128 * 32];

    const int tid  = threadIdx.x;
    const int wave = tid >> 6;
    const int lane = tid & 63;
    const int quad = lane >> 4;
    const int l16  = lane & 15;
    const int wm   = (wave & 1) << 6;
    const int wn   = (wave >> 1) << 6;
    const int bm   = blockIdx.x;
    const int bn   = blockIdx.y;

    floatx4 acc[4][4] = {};

    const int v0 = tid * 8;
    const int r0 = v0 >> 5, c0 = v0 & 31;
    const int v1 = (256 + tid) * 8;
    const int r1 = v1 >> 5, c1 = v1 & 31;

    const short* Abase = A + (size_t)bm * 128 * K;
    const short* Bbase = Bm + (size_t)bn * 128 * K;

    for (int k0 = 0; k0 < K; k0 += 32) {
        __syncthreads();
        __builtin_amdgcn_global_load_lds(
            (const __attribute__((address_space(1))) unsigned int*)(Abase + (size_t)r0 * K + k0 + c0),
            (__attribute__((address_space(3))) unsigned int*)(As + wave * 512), 16, 0, 0);
        __builtin_amdgcn_global_load_lds(
            (const __attribute__((address_space(1))) unsigned int*)(Abase + (size_t)r1 * K + k0 + c1),
            (__attribute__((address_space(3))) unsigned int*)(As + 2048 + wave * 512), 16, 0, 0);
        __builtin_amdgcn_global_load_lds(
            (const __attribute__((address_space(1))) unsigned int*)(Bbase + (size_t)r0 * K + k0 + c0),
            (__attribute__((address_space(3))) unsigned int*)(Bs + wave * 512), 16, 0, 0);
        __builtin_amdgcn_global_load_lds(
            (const __attribute__((address_space(1))) unsigned int*)(Bbase + (size_t)r1 * K + k0 + c1),
            (__attribute__((address_space(3))) unsigned int*)(Bs + 2048 + wave * 512), 16, 0, 0);
        __syncthreads();

        shortx8 af[4], bfv[4];
#pragma unroll
        for (int i = 0; i < 4; ++i)
            af[i] = *(const shortx8*)(As + (wm + i * 16 + l16) * 32 + quad * 8);
#pragma unroll
        for (int j = 0; j < 4; ++j)
            bfv[j] = *(const shortx8*)(Bs + (wn + j * 16 + l16) * 32 + quad * 8);
#pragma unroll
        for (int i = 0; i < 4; ++i)
#pragma unroll
            for (int j = 0; j < 4; ++j)
                acc[i][j] = __builtin_amdgcn_mfma_f32_16x16x32_bf16(af[i], bfv[j], acc[i][j], 0, 0, 0);
    }

    // fused epilogue; bn<16 -> x half, else z half (block-uniform branch)
    if (bn < 16) {
#pragma unroll
        for (int j = 0; j < 4; ++j) {
            int d = bn * 128 + wn + j * 16 + l16;          // 0..2047
            float4 w4 = *(const float4*)(conv_w + d * 4);
            float cb = conv_b[d];
#pragma unroll
            for (int i = 0; i < 4; ++i) {
                int gm = bm * 128 + wm + i * 16 + quad * 4;
#pragma unroll
                for (int r = 0; r < 4; ++r) {
                    size_t idx = (size_t)(gm + r) * 2048 + d;
                    float xv = acc[i][j][r];
                    float4 cs = *(const float4*)(conv_state + idx * 4);
                    float s = cs.y * w4.x + cs.z * w4.y + cs.w * w4.z + xv * w4.w + cb;
                    float xc = s * sig_(s);
                    float4 outv = {cs.y, cs.z, cs.w, xv};
                    *(float4*)(conv_out + idx * 4) = outv;
                    x_conv[idx] = xc;
                    x_conv_bf[idx] = bfc(xc);
                }
            }
        }
    } else {
#pragma unroll
        for (int j = 0; j < 4; ++j) {
            int d = bn * 128 + wn + j * 16 + l16 - 2048;   // 0..2047
#pragma unroll
            for (int i = 0; i < 4; ++i) {
                int gm = bm * 128 + wm + i * 16 + quad * 4;
#pragma unroll
                for (int r = 0; r < 4; ++r) {
                    float zv = acc[i][j][r];
                    zs[(size_t)(gm + r) * 2048 + d] = zv * sig_(zv);
                }
            }
        }
    }
}

// sum split-K partials: x_db[b][n] (n<96) = sum_z part[z][b][n] (ld 128)
__global__ __launch_bounds__(256) void reduce_g3(
    const float* __restrict__ part, float* __restrict__ x_db)
{
    int idx = blockIdx.x * 256 + threadIdx.x;  // over 2048*96
    int b = idx / 96, n = idx - b * 96;
    float s = 0.f;
#pragma unroll
    for (int z = 0; z < 8; ++z)
        s += part[(size_t)z * BATCH * 128 + b * 128 + n];
    x_db[idx] = s;
}

// dt_full = softplus(x_db[:, :64] @ dt_w.T + dt_b); 8 batch rows per block so
// each dt_w float4 load is reused 8x in registers (dt_w L2 traffic /8).
__global__ __launch_bounds__(256) void dt_kernel(
    const float* __restrict__ x_db, const float* __restrict__ dt_w,
    const float* __restrict__ dt_b, float* __restrict__ dt_full)
{
    __shared__ float dtp[8][64];
    int tid = threadIdx.x;
    int b0 = blockIdx.y * 8;
    {
        int bb = tid >> 5, k = tid & 31;
        dtp[bb][k]      = x_db[(b0 + bb) * 96 + k];
        dtp[bb][k + 32] = x_db[(b0 + bb) * 96 + k + 32];
    }
    __syncthreads();
    int d = blockIdx.x * 256 + tid;
    float acc[8];
    float bv = dt_b[d];
#pragma unroll
    for (int bb = 0; bb < 8; ++bb) acc[bb] = bv;
    const float4* w = (const float4*)(dt_w + d * 64);
#pragma unroll
    for (int k4 = 0; k4 < 16; ++k4) {
        float4 wv = w[k4];
#pragma unroll
        for (int bb = 0; bb < 8; ++bb) {
            acc[bb] += dtp[bb][k4 * 4 + 0] * wv.x + dtp[bb][k4 * 4 + 1] * wv.y +
                       dtp[bb][k4 * 4 + 2] * wv.z + dtp[bb][k4 * 4 + 3] * wv.w;
        }
    }
#pragma unroll
    for (int bb = 0; bb < 8; ++bb) {
        float a = acc[bb];
        float sp = a > 20.f ? a : log1pf(__expf(a));
        dt_full[(size_t)(b0 + bb) * 2048 + d] = sp;
    }
}

// SSM state update + y = (ssm_new . C + D*x) * zs.  4 lanes per channel
// (q = tid&3 owns one float4 quad of the 16 states) -> state loads/stores are
// contiguous 16B per lane = fully coalesced 1KB/wave.
__global__ __launch_bounds__(256) void ssm_kernel(
    const float* __restrict__ ssm_state, const float* __restrict__ x_conv,
    const float* __restrict__ dt_full, const float* __restrict__ zs,
    const float* __restrict__ x_db, const float* __restrict__ A_neg,
    const float* __restrict__ Dvec, float* __restrict__ ssm_out,
    unsigned short* __restrict__ y_bf)
{
    __shared__ float BC[32];  // B then C for this batch row
    int b = blockIdx.y;
    int tid = threadIdx.x;
    if (tid < 32) BC[tid] = x_db[b * 96 + 64 + tid];
    __syncthreads();
    int q  = tid & 3;
    int d  = blockIdx.x * 64 + (tid >> 2);
    size_t idx = (size_t)b * 2048 + d;
    float x  = x_conv[idx];
    float dt = dt_full[idx];
    float xdt = x * dt;
    float4 s = *(const float4*)(ssm_state + idx * 16 + q * 4);
    float4 a = *(const float4*)(A_neg + d * 16 + q * 4);
    float4 o;
    o.x = s.x * __expf(dt * a.x) + xdt * BC[q * 4 + 0];
    o.y = s.y * __expf(dt * a.y) + xdt * BC[q * 4 + 1];
    o.z = s.z * __expf(dt * a.z) + xdt * BC[q * 4 + 2];
    o.w = s.w * __expf(dt * a.w) + xdt * BC[q * 4 + 3];
    *(float4*)(ssm_out + idx * 16 + q * 4) = o;
    float p = o.x * BC[16 + q * 4 + 0] + o.y * BC[16 + q * 4 + 1] +
              o.z * BC[16 + q * 4 + 2] + o.w * BC[16 + q * 4 + 3];
    p += __shfl_xor(p, 1);
    p += __shfl_xor(p, 2);
    if (q == 0) {
        float y = p + Dvec[d] * x;
        y *= zs[idx];
        y_bf[idx] = bfc(y);
    }
}

// Wc[j][d] = sum_m head_w[j][m] * out_proj_w[m][d]   (fp32; j=18 is val_w)
__global__ __launch_bounds__(256) void fold_heads(
    const float* __restrict__ opw, const float* __restrict__ pol_w,
    const float* __restrict__ val_w, float* __restrict__ Wc)
{
    __shared__ float hw[1024];
    int j = blockIdx.y;
    const float* src = (j < 18) ? (pol_w + j * 1024) : val_w;
    for (int t = threadIdx.x; t < 1024; t += 256) hw[t] = src[t];
    __syncthreads();
    int d = blockIdx.x * 256 + threadIdx.x;
    float acc = 0.f;
#pragma unroll 8
    for (int m = 0; m < 1024; ++m)
        acc += hw[m] * opw[(size_t)m * 2048 + d];
    Wc[j * 2048 + d] = acc;
}

// logits[b][j] = sum_d y[b][d] * Wc[j][d] + pol_b[j]; value likewise (j=18)
__global__ __launch_bounds__(256) void heads_kernel(
    const unsigned short* __restrict__ y_bf, const float* __restrict__ Wc,
    const float* __restrict__ pol_b, const float* __restrict__ val_b,
    float* __restrict__ logits, float* __restrict__ value)
{
    __shared__ __align__(16) float row[2048];
    int b = blockIdx.x;
    int tid = threadIdx.x;
    shortx8 v = ((const shortx8*)(y_bf + (size_t)b * 2048))[tid];
#pragma unroll
    for (int e = 0; e < 8; ++e) {
        unsigned int u = ((unsigned int)(unsigned short)v[e]) << 16;
        row[tid * 8 + e] = *(float*)&u;
    }
    __syncthreads();
    int wave = tid >> 6, lane = tid & 63;
    for (int j = wave; j < 19; j += 4) {
        const float4* w = (const float4*)(Wc + j * 2048);
        float p = 0.f;
        for (int k4 = lane; k4 < 512; k4 += 64) {
            float4 wv = w[k4];
            float4 rv = ((const float4*)row)[k4];
            p += rv.x * wv.x + rv.y * wv.y + rv.z * wv.z + rv.w * wv.w;
        }
#pragma unroll
        for (int off = 32; off; off >>= 1) p += __shfl_down(p, off);
        if (lane == 0) {
            if (j < 18) logits[b * NACT + j] = p + pol_b[j];
            else        value[b] = p + val_b[0];
        }
    }
}

// ---------------------------------------------------------------------------
extern "C" void kernel_launch(void* const* d_in, const int* in_sizes, int n_in,
                              void* d_out, int out_size, void* d_ws, size_t ws_size,
                              hipStream_t stream)
{
    const float* obs        = (const float*)d_in[0];
    const float* conv_state = (const float*)d_in[1];
    const float* ssm_state  = (const float*)d_in[2];
    const float* in_proj_w  = (const float*)d_in[3];
    const float* in_proj_b  = (const float*)d_in[4];
    const float* mamba_in_w = (const float*)d_in[5];
    const float* conv_w     = (const float*)d_in[6];
    const float* conv_b     = (const float*)d_in[7];
    const float* x_proj_w   = (const float*)d_in[8];
    const float* dt_w       = (const float*)d_in[9];
    const float* dt_b       = (const float*)d_in[10];
    const float* A_log      = (const float*)d_in[11];
    const float* Dvec       = (const float*)d_in[12];
    const float* out_proj_w = (const float*)d_in[13];
    const float* pol_w      = (const float*)d_in[14];
    const float* pol_b      = (const float*)d_in[15];
    const float* val_w      = (const float*)d_in[16];
    const float* val_b      = (const float*)d_in[17];

    // workspace layout (bytes)
    char* ws = (char*)d_ws;
    unsigned short* obs_bf    = (unsigned short*)(ws + 0);          // 2048x512 bf16
    unsigned short* w1_bf     = (unsigned short*)(ws + 2097152);    // 1024x512
    unsigned short* w2_bf     = (unsigned short*)(ws + 3145728);    // 4096x1024
    unsigned short* w3_bf     = (unsigned short*)(ws + 11534336);   // 128x2048 (padded)
    float*          A_neg     = (float*)(ws + 12058624);            // 2048x16
    unsigned short* h_bf      = (unsigned short*)(ws + 12189696);   // 2048x1024
    float*          x_conv    = (float*)(ws + 16384000);            // 2048x2048 fp32
    unsigned short* x_conv_bf = (unsigned short*)(ws + 33161216);   // 2048x2048 bf16
    float*          zs        = (float*)(ws + 41549824);            // 2048x2048 fp32
    float*          g3_part   = (float*)(ws + 58327040);            // 8x2048x128
    float*          x_db      = (float*)(ws + 66715648);            // 2048x96
    float*          dt_full   = (float*)(ws + 67502080);            // 2048x2048
    unsigned short* y_bf      = (unsigned short*)(ws + 84279296);   // 2048x2048 bf16
    float*          Wc        = (float*)(ws + 92667904);            // 19x2048
    // total = 92,823,552 bytes
    if (ws_size < 92823552) return;  // insufficient workspace -> fail loudly

    float* logits   = (float*)d_out;                       // 2048x18
    float* value    = logits + (size_t)BATCH * NACT;       // 2048
    float* conv_out = value + BATCH;                       // 2048x2048x4
    float* ssm_out  = conv_out + (size_t)BATCH * DINNER * 4;  // 2048x2048x16

    convert_kernel<<<5920, 256, 0, stream>>>(obs, in_proj_w, mamba_in_w, x_proj_w,
                                             A_log, obs_bf, w1_bf, w2_bf, w3_bf,
                                             A_neg);

    // Wc = [pol_w; val_w] @ out_proj_w  (fp32, replaces G5 entirely)
    fold_heads<<<dim3(8, 19), 256, 0, stream>>>(out_proj_w, pol_w, val_w, Wc);

    // G1: h = obs @ in_proj_w.T + b  -> bf16
    gemm_bt<1, 1, 0><<<dim3(16, 8), 256, 0, stream>>>(
        (const short*)obs_bf, (const short*)w1_bf, h_bf, in_proj_b, 2048, 1024, 512, 0);

    // G2: xz = h @ mamba_in_w.T with fused conv (x half) + z*sig(z) (z half)
    gemm_g2<<<dim3(16, 32), 256, 0, stream>>>(
        (const short*)h_bf, (const short*)w2_bf, conv_state, conv_w, conv_b,
        conv_out, x_conv, x_conv_bf, zs, 1024);

    // G3: x_db = x_conv @ x_proj_w.T  (N padded 96->128, split-K=8)
    gemm_bt<0, 0, 1><<<dim3(16, 1, 8), 256, 0, stream>>>(
        (const short*)x_conv_bf, (const short*)w3_bf, g3_part, nullptr, 2048, 128, 2048, 256);
    reduce_g3<<<768, 256, 0, stream>>>(g3_part, x_db);

    dt_kernel<<<dim3(8, 256), 256, 0, stream>>>(x_db, dt_w, dt_b, dt_full);

    ssm_kernel<<<dim3(32, 2048), 256, 0, stream>>>(ssm_state, x_conv, dt_full, zs,
                                                   x_db, A_neg, Dvec, ssm_out, y_bf);

    heads_kernel<<<2048, 256, 0, stream>>>(y_bf, Wc, pol_b, val_b, logits, value);
}